// Round 18
// baseline (123.758 us; speedup 1.0000x reference)
//
#include <hip/hip_runtime.h>
#include <hip/hip_bf16.h>
#include <type_traits>

// Dims: B=8, L=2048, T=1024, Dh=1024, Dg=768, Dp=256
// Pipeline: [HT,Hbf]=transpose+cast(H)[+castW+rowsum-zero]; {Q,K}=proj (merged);
//           Sexp=exp(Q@K^T/16)[+rowsum]; Z=(Sexp@HT^T)/rowsum
// R18: sgemm -> 128^2 / BK=64 / 4-wave / 2-buf prefetch (PV's winning loop, 48KB LDS,
//      3 blocks/CU). transp/proj/pv = R17 measured-best.

typedef float    f32x4  __attribute__((ext_vector_type(4)));
typedef __bf16   bf16x8 __attribute__((ext_vector_type(8)));
typedef unsigned short u16x8 __attribute__((ext_vector_type(8)));

__device__ __forceinline__ unsigned short f2bf(float f) {
    union { __bf16 b; unsigned short u; } c;
    c.b = (__bf16)f;
    return c.u;
}
__device__ __forceinline__ float bf2f(unsigned short u) {
    union { unsigned u; float f; } x; x.u = ((unsigned)u) << 16;
    return x.f;
}
__device__ __forceinline__ void gload_lds16(const unsigned short* g, unsigned short* l) {
    __builtin_amdgcn_global_load_lds(
        (const __attribute__((address_space(1))) void*)g,
        (__attribute__((address_space(3))) void*)l, 16, 0, 0);
}

// ---- transpose + dual cast + fused W-cast / rowsum-zero (unchanged R17) ----
__global__ __launch_bounds__(256) void kn_transp(const float* __restrict__ H,
                                                 unsigned short* __restrict__ HT,
                                                 unsigned short* __restrict__ Hbf,
                                                 const float* __restrict__ Wq,
                                                 const float* __restrict__ Wk,
                                                 unsigned short* __restrict__ Wqbf,
                                                 unsigned short* __restrict__ Wkbf,
                                                 float* __restrict__ rowsum,
                                                 int L, int D, int nq8, int nk8, int nrs4) {
    __shared__ float tile[64][65];
    int b = blockIdx.z;
    const float* src = H + (size_t)b * L * D;
    unsigned short* dstT = HT + (size_t)b * L * D;
    unsigned short* dstN = Hbf + (size_t)b * L * D;
    int l0 = blockIdx.y * 64, d0 = blockIdx.x * 64;
    int rh = threadIdx.x >> 3;
    int c8 = (threadIdx.x & 7) * 8;

    int fid = blockIdx.x + gridDim.x * (blockIdx.y + gridDim.y * blockIdx.z);
    if (fid == 0) {
        f32x4 z = {};
        for (int j = threadIdx.x; j < nrs4; j += 256)
            *(f32x4*)(rowsum + (size_t)j * 4) = z;
    }
    {
        int i = fid * 256 + threadIdx.x;
        if (i < nq8 + nk8) {
            const float* s;
            unsigned short* dp;
            int idx;
            if (i < nq8) { idx = i; s = Wq; dp = Wqbf; }
            else         { idx = i - nq8; s = Wk; dp = Wkbf; }
            f32x4 a = *(const f32x4*)(s + (size_t)idx * 8);
            f32x4 bb = *(const f32x4*)(s + (size_t)idx * 8 + 4);
            u16x8 o;
#pragma unroll
            for (int j = 0; j < 4; ++j) { o[j] = f2bf(a[j]); o[4 + j] = f2bf(bb[j]); }
            *(u16x8*)(dp + (size_t)idx * 8) = o;
        }
    }

#pragma unroll
    for (int i = 0; i < 2; ++i) {
        int r = rh + i * 32;
        const float* p = &src[(size_t)(l0 + r) * D + d0 + c8];
        f32x4 v0 = *(const f32x4*)p;
        f32x4 v1 = *(const f32x4*)(p + 4);
        u16x8 o;
#pragma unroll
        for (int j = 0; j < 4; ++j) {
            o[j] = f2bf(v0[j]); o[4 + j] = f2bf(v1[j]);
            tile[r][c8 + j] = v0[j];
            tile[r][c8 + 4 + j] = v1[j];
        }
        *(u16x8*)&dstN[(size_t)(l0 + r) * D + d0 + c8] = o;
    }
    __syncthreads();
#pragma unroll
    for (int i = 0; i < 2; ++i) {
        int d = rh + i * 32;
        u16x8 o;
#pragma unroll
        for (int j = 0; j < 8; ++j) o[j] = f2bf(tile[c8 + j][d]);
        *(u16x8*)&dstT[(size_t)(d0 + d) * L + l0 + c8] = o;
    }
}

// -------- qproj body (unchanged R17) --------
__device__ __forceinline__ void qproj_body(char* smem_raw,
                                           const float* __restrict__ A,
                                           const unsigned short* __restrict__ B,
                                           unsigned short* __restrict__ C,
                                           int N, int K, int t) {
    unsigned short* sA = (unsigned short*)smem_raw;
    unsigned short* sB = sA + 32 * 64;
    float* st = (float*)smem_raw;

    int tid = threadIdx.x;
    int by = t >> 1;
    int bx = t & 1;
    const float* Ab = A + (size_t)by * 32 * K;
    const unsigned short* Bb = B + (size_t)bx * 128 * K;

    int lane = tid & 63;
    int wid = tid >> 6;
    int lr = lane & 15;
    int lg = lane >> 4;
    int xoff = (lane & 7) << 3;

    f32x4 acc[2][2] = {};

    for (int k0 = 0; k0 < K; k0 += 64) {
#pragma unroll
        for (int c = 0; c < 4; ++c) {
            int ch = c * 256 + tid;
            int row = ch >> 3;
            int g8 = (ch & 7) ^ (row & 7);
            gload_lds16(Bb + (size_t)row * K + k0 + g8 * 8, sB + ch * 8);
        }
        {
            int ch = tid;
            int row = ch >> 3;
            const float* srcp = Ab + (size_t)row * K + k0 + (ch & 7) * 8;
            f32x4 v0 = *(const f32x4*)srcp;
            f32x4 v1 = *(const f32x4*)(srcp + 4);
            u16x8 o;
#pragma unroll
            for (int j = 0; j < 4; ++j) { o[j] = f2bf(v0[j]); o[4 + j] = f2bf(v1[j]); }
            int sl = (ch & 7) ^ (row & 7);
            *(u16x8*)&sA[row * 64 + sl * 8] = o;
        }
        __syncthreads();
#pragma unroll
        for (int kk = 0; kk < 2; ++kk) {
            int kb = (kk * 32 + lg * 8) ^ xoff;
            bf16x8 af[2], bfr[2];
#pragma unroll
            for (int m = 0; m < 2; ++m)
                af[m] = *(const bf16x8*)&sA[(m * 16 + lr) * 64 + kb];
#pragma unroll
            for (int n = 0; n < 2; ++n)
                bfr[n] = *(const bf16x8*)&sB[(wid * 32 + n * 16 + lr) * 64 + kb];
#pragma unroll
            for (int m = 0; m < 2; ++m)
#pragma unroll
                for (int n = 0; n < 2; ++n)
                    acc[m][n] = __builtin_amdgcn_mfma_f32_16x16x32_bf16(af[m], bfr[n], acc[m][n], 0, 0, 0);
        }
        __syncthreads();
    }

#pragma unroll
    for (int m = 0; m < 2; ++m) {
        int r0 = m * 16 + lg * 4;
#pragma unroll
        for (int n = 0; n < 2; ++n) {
            int c0 = wid * 32 + n * 16 + lr;
#pragma unroll
            for (int j = 0; j < 4; ++j)
                st[(r0 + j) * 132 + c0] = acc[m][n][j];
        }
    }
    __syncthreads();
    int r  = tid >> 3;
    int c0 = (tid & 7) * 16;
    size_t grow = (size_t)(by * 32 + r) * N + bx * 128 + c0;
#pragma unroll
    for (int g = 0; g < 2; ++g) {
        f32x4 a = *(const f32x4*)&st[r * 132 + c0 + g * 8];
        f32x4 b = *(const f32x4*)&st[r * 132 + c0 + g * 8 + 4];
        u16x8 o;
#pragma unroll
        for (int j = 0; j < 4; ++j) { o[j] = f2bf(a[j]); o[4 + j] = f2bf(b[j]); }
        *(u16x8*)&C[grow + g * 8] = o;
    }
}

// -------- kproj body (unchanged R17) --------
__device__ __forceinline__ void kproj_body(char* smem_raw,
                                           const unsigned short* __restrict__ A,
                                           const unsigned short* __restrict__ B,
                                           unsigned short* __restrict__ C,
                                           int N, int K, int t) {
    unsigned short* sA = (unsigned short*)smem_raw;
    unsigned short* sB = sA + 64 * 64;
    float* st = (float*)smem_raw;

    int tid = threadIdx.x;
    int by = t >> 1;
    int bx = t & 1;
    const unsigned short* Ab = A + (size_t)by * 64 * K;
    const unsigned short* Bb = B + (size_t)bx * 128 * K;

    int lane = tid & 63;
    int wid = tid >> 6;
    int wr = wid >> 1, wc = wid & 1;
    int lr = lane & 15;
    int lg = lane >> 4;
    int xoff = (lane & 7) << 3;

    f32x4 acc[2][4] = {};

    for (int k0 = 0; k0 < K; k0 += 64) {
#pragma unroll
        for (int c = 0; c < 2; ++c) {
            int ch = c * 256 + tid;
            int row = ch >> 3;
            int g8 = (ch & 7) ^ (row & 7);
            gload_lds16(Ab + (size_t)row * K + k0 + g8 * 8, sA + ch * 8);
        }
#pragma unroll
        for (int c = 0; c < 4; ++c) {
            int ch = c * 256 + tid;
            int row = ch >> 3;
            int g8 = (ch & 7) ^ (row & 7);
            gload_lds16(Bb + (size_t)row * K + k0 + g8 * 8, sB + ch * 8);
        }
        __syncthreads();
#pragma unroll
        for (int kk = 0; kk < 2; ++kk) {
            int kb = (kk * 32 + lg * 8) ^ xoff;
            bf16x8 af[2], bfr[4];
#pragma unroll
            for (int m = 0; m < 2; ++m)
                af[m] = *(const bf16x8*)&sA[(wr * 32 + m * 16 + lr) * 64 + kb];
#pragma unroll
            for (int n = 0; n < 4; ++n)
                bfr[n] = *(const bf16x8*)&sB[(wc * 64 + n * 16 + lr) * 64 + kb];
#pragma unroll
            for (int m = 0; m < 2; ++m)
#pragma unroll
                for (int n = 0; n < 4; ++n)
                    acc[m][n] = __builtin_amdgcn_mfma_f32_16x16x32_bf16(af[m], bfr[n], acc[m][n], 0, 0, 0);
        }
        __syncthreads();
    }

#pragma unroll
    for (int m = 0; m < 2; ++m) {
        int r0 = wr * 32 + m * 16 + lg * 4;
#pragma unroll
        for (int n = 0; n < 4; ++n) {
            int c0 = wc * 64 + n * 16 + lr;
#pragma unroll
            for (int j = 0; j < 4; ++j)
                st[(r0 + j) * 132 + c0] = acc[m][n][j];
        }
    }
    __syncthreads();
    int r  = tid >> 2;
    int c0 = (tid & 3) * 32;
    size_t grow = (size_t)(by * 64 + r) * N + bx * 128 + c0;
#pragma unroll
    for (int g = 0; g < 4; ++g) {
        f32x4 a = *(const f32x4*)&st[r * 132 + c0 + g * 8];
        f32x4 b = *(const f32x4*)&st[r * 132 + c0 + g * 8 + 4];
        u16x8 o;
#pragma unroll
        for (int j = 0; j < 4; ++j) { o[j] = f2bf(a[j]); o[4 + j] = f2bf(b[j]); }
        *(u16x8*)&C[grow + g * 8] = o;
    }
}

__global__ __launch_bounds__(256) void kn_proj(const unsigned short* __restrict__ Hbf,
                                               const unsigned short* __restrict__ Wkbf,
                                               unsigned short* __restrict__ Kbf,
                                               const float* __restrict__ G,
                                               const unsigned short* __restrict__ Wqbf,
                                               unsigned short* __restrict__ Qbf,
                                               int Dp, int Dh, int Dg) {
    __shared__ __align__(16) char smem_raw[64 * 132 * 4];
    int wg = blockIdx.x;
    if (wg < 512) kproj_body(smem_raw, Hbf, Wkbf, Kbf, Dp, Dh, wg);
    else          qproj_body(smem_raw, G, Wqbf, Qbf, Dp, Dg, wg - 512);
}

// ------- S-GEMM R18: 128x128, BK=64, 4 waves (2Mx2N), 2-buf prefetch loop (48KB LDS,
//         3 blocks/CU). Epilogue: exp + bf16 store + rowsum atomics. -------
__global__ __launch_bounds__(256) void kn_sgemm(const unsigned short* __restrict__ A,
                                               const unsigned short* __restrict__ B,
                                               unsigned short* __restrict__ C,
                                               float* __restrict__ rowsum,
                                               int N, int K, int Trows,
                                               long batchA, long batchB, long batchC,
                                               float scale, int gxs) {
    __shared__ __align__(16) char smem_raw[2 * 32768];       // 2 bufs x (A 16KB + B 16KB)
    unsigned short* base = (unsigned short*)smem_raw;
    float* st = (float*)smem_raw;                            // epilogue 64x132 f32 = 33.8KB

    int tid = threadIdx.x;
    int wg = blockIdx.x;
    int bz = wg & 7;
    int t = wg >> 3;
    int by = t >> gxs;
    int bx = t & ((1 << gxs) - 1);

    const unsigned short* Ab = A + (size_t)bz * batchA + (size_t)by * 128 * K;
    const unsigned short* Bb = B + (size_t)bz * batchB + (size_t)bx * 128 * K;
    unsigned short* Cb = C + (size_t)bz * batchC;
    float* rs = rowsum + (size_t)bz * Trows;

    int lane = tid & 63;
    int wid = tid >> 6;
    int wr = wid >> 1, wc = wid & 1;      // 2M x 2N; wave-tile 64x64
    int lr = lane & 15;
    int lg = lane >> 4;
    int xoff = (lane & 7) << 3;

    f32x4 acc[4][4] = {};

    auto STAGE = [&](int buf, int k0) {   // A 1024 chunks + B 1024 chunks, 8/thread
        unsigned short* dA = base + buf * 16384;
        unsigned short* dB = dA + 8192;
#pragma unroll
        for (int c = 0; c < 8; ++c) {
            int ch = (c & 3) * 256 + tid;          // 0..1023
            int row = ch >> 3;
            int g8 = (ch & 7) ^ (row & 7);
            if (c < 4) gload_lds16(Ab + (size_t)row * K + k0 + g8 * 8, dA + ch * 8);
            else       gload_lds16(Bb + (size_t)row * K + k0 + g8 * 8, dB + ch * 8);
        }
    };
    auto COMPUTE = [&](int buf) {
        unsigned short* pA = base + buf * 16384;
        unsigned short* pB = pA + 8192;
#pragma unroll
        for (int kk = 0; kk < 2; ++kk) {
            int kb = (kk * 32 + lg * 8) ^ xoff;
            bf16x8 af[4], bfr[4];
#pragma unroll
            for (int m = 0; m < 4; ++m)
                af[m] = *(const bf16x8*)&pA[(wr * 64 + m * 16 + lr) * 64 + kb];
#pragma unroll
            for (int n = 0; n < 4; ++n)
                bfr[n] = *(const bf16x8*)&pB[(wc * 64 + n * 16 + lr) * 64 + kb];
#pragma unroll
            for (int m = 0; m < 4; ++m)
#pragma unroll
                for (int n = 0; n < 4; ++n)
                    acc[m][n] = __builtin_amdgcn_mfma_f32_16x16x32_bf16(af[m], bfr[n], acc[m][n], 0, 0, 0);
        }
    };

    int nt = K / 64;                       // 4
    STAGE(0, 0);
    __syncthreads();
    int cur = 0;
    for (int tt = 0; tt < nt; ++tt) {
        if (tt + 1 < nt) STAGE(cur ^ 1, (tt + 1) * 64);
        COMPUTE(cur);
        __syncthreads();
        cur ^= 1;
    }

    // epilogue: two 64-row halves via st[64][132]; exp + store + rowsum atomics
#pragma unroll
    for (int half = 0; half < 2; ++half) {
        if (wr == half) {
#pragma unroll
            for (int m = 0; m < 4; ++m) {
                int rl = m * 16 + lg * 4;
#pragma unroll
                for (int n = 0; n < 4; ++n) {
                    int col = wc * 64 + n * 16 + lr;
#pragma unroll
                    for (int j = 0; j < 4; ++j)
                        st[(rl + j) * 132 + col] = acc[m][n][j] * scale;
                }
            }
        }
        __syncthreads();
        int r = tid >> 2;                  // 0..63
        int c0 = (tid & 3) * 32;           // 0,32,64,96
        int grow_r = by * 128 + half * 64 + r;
        size_t grow = (size_t)grow_r * N + bx * 128 + c0;
        float psum = 0.f;
#pragma unroll
        for (int g = 0; g < 4; ++g) {
            f32x4 a = *(const f32x4*)&st[r * 132 + c0 + g * 8];
            f32x4 b = *(const f32x4*)&st[r * 132 + c0 + g * 8 + 4];
            u16x8 o;
#pragma unroll
            for (int j = 0; j < 4; ++j) {
                o[j]     = f2bf(__expf(a[j]));
                o[4 + j] = f2bf(__expf(b[j]));
                psum += bf2f(o[j]) + bf2f(o[4 + j]);
            }
            *(u16x8*)&Cb[grow + g * 8] = o;
        }
        psum += __shfl_xor(psum, 1);
        psum += __shfl_xor(psum, 2);
        if ((tid & 3) == 0)
            atomicAdd(&rs[grow_r], psum);
        __syncthreads();
    }
}

// ------- PV (unchanged R17 winner): 256x128, BK=64, 2-buf prefetch, rowsum divide -------
__global__ __launch_bounds__(512) void kn_pv(const unsigned short* __restrict__ A,
                                             const unsigned short* __restrict__ B,
                                             float* __restrict__ C,
                                             const float* __restrict__ rowsum,
                                             int N, int K, int Trows,
                                             long batchA, long batchB, long batchC,
                                             int gxs) {
    __shared__ __align__(16) char smem_raw[2 * 49152];       // 96KB
    unsigned short* base = (unsigned short*)smem_raw;
    float* st = (float*)smem_raw;

    int tid = threadIdx.x;
    int wg = blockIdx.x;
    int bz = wg & 7;
    int t = wg >> 3;
    int by = t >> gxs;
    int bx = t & ((1 << gxs) - 1);

    const unsigned short* Ab = A + (size_t)bz * batchA + (size_t)by * 256 * K;
    const unsigned short* Bb = B + (size_t)bz * batchB + (size_t)bx * 128 * K;
    float* Cb = C + (size_t)bz * batchC;
    const float* rs = rowsum + (size_t)bz * Trows;

    int lane = tid & 63;
    int wid = tid >> 6;
    int wr = wid >> 1, wc = wid & 1;
    int lr = lane & 15;
    int lg = lane >> 4;
    int xoff = (lane & 7) << 3;

    f32x4 acc[4][4] = {};

    auto STAGE = [&](int buf, int k0) {
        unsigned short* dA = base + buf * 24576;
        unsigned short* dB = dA + 16384;
#pragma unroll
        for (int c = 0; c < 6; ++c) {
            int ch = c * 512 + tid;
            if (ch < 2048) {
                int row = ch >> 3;
                int g8 = (ch & 7) ^ (row & 7);
                gload_lds16(Ab + (size_t)row * K + k0 + g8 * 8, dA + ch * 8);
            } else {
                int bc = ch - 2048;
                int row = bc >> 3;
                int g8 = (bc & 7) ^ (row & 7);
                gload_lds16(Bb + (size_t)row * K + k0 + g8 * 8, dB + bc * 8);
            }
        }
    };
    auto COMPUTE = [&](int buf) {
        unsigned short* pA = base + buf * 24576;
        unsigned short* pB = pA + 16384;
#pragma unroll
        for (int kk = 0; kk < 2; ++kk) {
            int kb = (kk * 32 + lg * 8) ^ xoff;
            bf16x8 af[4], bfr[4];
#pragma unroll
            for (int m = 0; m < 4; ++m)
                af[m] = *(const bf16x8*)&pA[(wr * 64 + m * 16 + lr) * 64 + kb];
#pragma unroll
            for (int n = 0; n < 4; ++n)
                bfr[n] = *(const bf16x8*)&pB[(wc * 64 + n * 16 + lr) * 64 + kb];
#pragma unroll
            for (int m = 0; m < 4; ++m)
#pragma unroll
                for (int n = 0; n < 4; ++n)
                    acc[m][n] = __builtin_amdgcn_mfma_f32_16x16x32_bf16(af[m], bfr[n], acc[m][n], 0, 0, 0);
        }
    };

    int nt = K / 64;
    STAGE(0, 0);
    __syncthreads();
    int cur = 0;
    for (int tt = 0; tt < nt; ++tt) {
        if (tt + 1 < nt) STAGE(cur ^ 1, (tt + 1) * 64);
        COMPUTE(cur);
        __syncthreads();
        cur ^= 1;
    }

#pragma unroll
    for (int q = 0; q < 4; ++q) {
        if (wr == q) {
#pragma unroll
            for (int m = 0; m < 4; ++m) {
                int rl = m * 16 + lg * 4;
#pragma unroll
                for (int n = 0; n < 4; ++n) {
                    int col = wc * 64 + n * 16 + lr;
#pragma unroll
                    for (int j = 0; j < 4; ++j)
                        st[(rl + j) * 132 + col] = acc[m][n][j];
                }
            }
        }
        __syncthreads();
        int r = tid >> 3;
        int c0 = (tid & 7) * 16;
        float inv = 1.0f / rs[by * 256 + q * 64 + r];
        size_t grow = (size_t)(by * 256 + q * 64 + r) * N + bx * 128 + c0;
#pragma unroll
        for (int g = 0; g < 4; ++g) {
            f32x4 v = *(const f32x4*)&st[r * 132 + c0 + g * 4];
#pragma unroll
            for (int j = 0; j < 4; ++j) v[j] *= inv;
            *(f32x4*)&Cb[grow + g * 4] = v;
        }
        __syncthreads();
    }
}

extern "C" void kernel_launch(void* const* d_in, const int* in_sizes, int n_in,
                              void* d_out, int out_size, void* d_ws, size_t ws_size,
                              hipStream_t stream) {
    constexpr int B = 8, L = 2048, T = 1024, Dh = 1024, Dg = 768, Dp = 256;
    const float* H  = (const float*)d_in[0];
    const float* G  = (const float*)d_in[1];
    const float* Wq = (const float*)d_in[2];
    const float* Wk = (const float*)d_in[3];
    float* Z = (float*)d_out;

    unsigned short* Qbf  = (unsigned short*)d_ws;
    unsigned short* Kbf  = Qbf + (size_t)B * T * Dp;
    unsigned short* HT   = Kbf + (size_t)B * L * Dp;
    unsigned short* S    = HT  + (size_t)B * Dh * L;
    unsigned short* Hbf  = S   + (size_t)B * T * L;
    unsigned short* Wqbf = Hbf + (size_t)B * L * Dh;
    unsigned short* Wkbf = Wqbf + (size_t)Dp * Dg;
    float* rowsum = (float*)(Wkbf + (size_t)Dp * Dh);

    int nq8 = Dp * Dg / 8, nk8 = Dp * Dh / 8;

    kn_transp<<<dim3(Dh / 64, L / 64, B), dim3(256), 0, stream>>>
        (H, HT, Hbf, Wq, Wk, Wqbf, Wkbf, rowsum, L, Dh, nq8, nk8, B * T / 4);

    kn_proj<<<1024, 256, 0, stream>>>(Hbf, Wkbf, Kbf, G, Wqbf, Qbf, Dp, Dh, Dg);

    // Sexp = exp(Q@K^T/16): 128^2 tiles, 2-buf prefetch; grid 8*16*8 = 1024
    kn_sgemm<<<(T / 128) * (L / 128) * B, 256, 0, stream>>>
        (Qbf, Kbf, S, rowsum, L, Dp, T, (long)T * Dp, (long)L * Dp, (long)T * L, 0.0625f, 4);

    kn_pv<<<(T / 256) * (Dh / 128) * B, 512, 0, stream>>>
        (S, HT, Z, rowsum, Dh, L, T, (long)T * L, (long)Dh * L, (long)T * Dh, 3);
}

// Round 19
// 119.295 us; speedup vs baseline: 1.0374x; 1.0374x over previous
//
#include <hip/hip_runtime.h>
#include <hip/hip_bf16.h>
#include <type_traits>

// Dims: B=8, L=2048, T=1024, Dh=1024, Dg=768, Dp=256
// Pipeline: [HT,Hbf]=transpose+cast(H) [+castW +rowsum-zero fused];
//           {Q,K}=proj (merged); Sexp=exp(Q@K^T/16)[+rowsum]; Z=(Sexp@HT^T)/rowsum
// R19 = R17 exact revert (session best: 119.3 us). R18's 128^2 sgemm regressed; the
// 256x128 8-wave single-buffer sgemm + 2-buf-prefetch PV are the measured winners.

typedef float    f32x4  __attribute__((ext_vector_type(4)));
typedef __bf16   bf16x8 __attribute__((ext_vector_type(8)));
typedef unsigned short u16x8 __attribute__((ext_vector_type(8)));

__device__ __forceinline__ unsigned short f2bf(float f) {
    union { __bf16 b; unsigned short u; } c;
    c.b = (__bf16)f;                       // native RNE cvt
    return c.u;
}
__device__ __forceinline__ float bf2f(unsigned short u) {
    union { unsigned u; float f; } x; x.u = ((unsigned)u) << 16;
    return x.f;
}
__device__ __forceinline__ void gload_lds16(const unsigned short* g, unsigned short* l) {
    __builtin_amdgcn_global_load_lds(
        (const __attribute__((address_space(1))) void*)g,
        (__attribute__((address_space(3))) void*)l, 16, 0, 0);
}

// ---- transpose + dual cast + fused W-cast / rowsum-zero ----
__global__ __launch_bounds__(256) void kn_transp(const float* __restrict__ H,
                                                 unsigned short* __restrict__ HT,
                                                 unsigned short* __restrict__ Hbf,
                                                 const float* __restrict__ Wq,
                                                 const float* __restrict__ Wk,
                                                 unsigned short* __restrict__ Wqbf,
                                                 unsigned short* __restrict__ Wkbf,
                                                 float* __restrict__ rowsum,
                                                 int L, int D, int nq8, int nk8, int nrs4) {
    __shared__ float tile[64][65];
    int b = blockIdx.z;
    const float* src = H + (size_t)b * L * D;
    unsigned short* dstT = HT + (size_t)b * L * D;
    unsigned short* dstN = Hbf + (size_t)b * L * D;
    int l0 = blockIdx.y * 64, d0 = blockIdx.x * 64;
    int rh = threadIdx.x >> 3;
    int c8 = (threadIdx.x & 7) * 8;

    int fid = blockIdx.x + gridDim.x * (blockIdx.y + gridDim.y * blockIdx.z);
    if (fid == 0) {                        // zero rowsum (8KB)
        f32x4 z = {};
        for (int j = threadIdx.x; j < nrs4; j += 256)
            *(f32x4*)(rowsum + (size_t)j * 4) = z;
    }
    {
        int i = fid * 256 + threadIdx.x;   // W-cast: chunks [0, nq8+nk8)
        if (i < nq8 + nk8) {
            const float* s;
            unsigned short* dp;
            int idx;
            if (i < nq8) { idx = i; s = Wq; dp = Wqbf; }
            else         { idx = i - nq8; s = Wk; dp = Wkbf; }
            f32x4 a = *(const f32x4*)(s + (size_t)idx * 8);
            f32x4 bb = *(const f32x4*)(s + (size_t)idx * 8 + 4);
            u16x8 o;
#pragma unroll
            for (int j = 0; j < 4; ++j) { o[j] = f2bf(a[j]); o[4 + j] = f2bf(bb[j]); }
            *(u16x8*)(dp + (size_t)idx * 8) = o;
        }
    }

#pragma unroll
    for (int i = 0; i < 2; ++i) {
        int r = rh + i * 32;
        const float* p = &src[(size_t)(l0 + r) * D + d0 + c8];
        f32x4 v0 = *(const f32x4*)p;
        f32x4 v1 = *(const f32x4*)(p + 4);
        u16x8 o;
#pragma unroll
        for (int j = 0; j < 4; ++j) {
            o[j] = f2bf(v0[j]); o[4 + j] = f2bf(v1[j]);
            tile[r][c8 + j] = v0[j];
            tile[r][c8 + 4 + j] = v1[j];
        }
        *(u16x8*)&dstN[(size_t)(l0 + r) * D + d0 + c8] = o;
    }
    __syncthreads();
#pragma unroll
    for (int i = 0; i < 2; ++i) {
        int d = rh + i * 32;
        u16x8 o;
#pragma unroll
        for (int j = 0; j < 8; ++j) o[j] = f2bf(tile[c8 + j][d]);
        *(u16x8*)&dstT[(size_t)(d0 + d) * L + l0 + c8] = o;
    }
}

// -------- qproj body --------
__device__ __forceinline__ void qproj_body(char* smem_raw,
                                           const float* __restrict__ A,
                                           const unsigned short* __restrict__ B,
                                           unsigned short* __restrict__ C,
                                           int N, int K, int t) {
    unsigned short* sA = (unsigned short*)smem_raw;
    unsigned short* sB = sA + 32 * 64;
    float* st = (float*)smem_raw;

    int tid = threadIdx.x;
    int by = t >> 1;
    int bx = t & 1;
    const float* Ab = A + (size_t)by * 32 * K;
    const unsigned short* Bb = B + (size_t)bx * 128 * K;

    int lane = tid & 63;
    int wid = tid >> 6;
    int lr = lane & 15;
    int lg = lane >> 4;
    int xoff = (lane & 7) << 3;

    f32x4 acc[2][2] = {};

    for (int k0 = 0; k0 < K; k0 += 64) {
#pragma unroll
        for (int c = 0; c < 4; ++c) {
            int ch = c * 256 + tid;
            int row = ch >> 3;
            int g8 = (ch & 7) ^ (row & 7);
            gload_lds16(Bb + (size_t)row * K + k0 + g8 * 8, sB + ch * 8);
        }
        {
            int ch = tid;
            int row = ch >> 3;
            const float* srcp = Ab + (size_t)row * K + k0 + (ch & 7) * 8;
            f32x4 v0 = *(const f32x4*)srcp;
            f32x4 v1 = *(const f32x4*)(srcp + 4);
            u16x8 o;
#pragma unroll
            for (int j = 0; j < 4; ++j) { o[j] = f2bf(v0[j]); o[4 + j] = f2bf(v1[j]); }
            int sl = (ch & 7) ^ (row & 7);
            *(u16x8*)&sA[row * 64 + sl * 8] = o;
        }
        __syncthreads();
#pragma unroll
        for (int kk = 0; kk < 2; ++kk) {
            int kb = (kk * 32 + lg * 8) ^ xoff;
            bf16x8 af[2], bfr[2];
#pragma unroll
            for (int m = 0; m < 2; ++m)
                af[m] = *(const bf16x8*)&sA[(m * 16 + lr) * 64 + kb];
#pragma unroll
            for (int n = 0; n < 2; ++n)
                bfr[n] = *(const bf16x8*)&sB[(wid * 32 + n * 16 + lr) * 64 + kb];
#pragma unroll
            for (int m = 0; m < 2; ++m)
#pragma unroll
                for (int n = 0; n < 2; ++n)
                    acc[m][n] = __builtin_amdgcn_mfma_f32_16x16x32_bf16(af[m], bfr[n], acc[m][n], 0, 0, 0);
        }
        __syncthreads();
    }

#pragma unroll
    for (int m = 0; m < 2; ++m) {
        int r0 = m * 16 + lg * 4;
#pragma unroll
        for (int n = 0; n < 2; ++n) {
            int c0 = wid * 32 + n * 16 + lr;
#pragma unroll
            for (int j = 0; j < 4; ++j)
                st[(r0 + j) * 132 + c0] = acc[m][n][j];
        }
    }
    __syncthreads();
    int r  = tid >> 3;
    int c0 = (tid & 7) * 16;
    size_t grow = (size_t)(by * 32 + r) * N + bx * 128 + c0;
#pragma unroll
    for (int g = 0; g < 2; ++g) {
        f32x4 a = *(const f32x4*)&st[r * 132 + c0 + g * 8];
        f32x4 b = *(const f32x4*)&st[r * 132 + c0 + g * 8 + 4];
        u16x8 o;
#pragma unroll
        for (int j = 0; j < 4; ++j) { o[j] = f2bf(a[j]); o[4 + j] = f2bf(b[j]); }
        *(u16x8*)&C[grow + g * 8] = o;
    }
}

// -------- kproj body --------
__device__ __forceinline__ void kproj_body(char* smem_raw,
                                           const unsigned short* __restrict__ A,
                                           const unsigned short* __restrict__ B,
                                           unsigned short* __restrict__ C,
                                           int N, int K, int t) {
    unsigned short* sA = (unsigned short*)smem_raw;
    unsigned short* sB = sA + 64 * 64;
    float* st = (float*)smem_raw;

    int tid = threadIdx.x;
    int by = t >> 1;
    int bx = t & 1;
    const unsigned short* Ab = A + (size_t)by * 64 * K;
    const unsigned short* Bb = B + (size_t)bx * 128 * K;

    int lane = tid & 63;
    int wid = tid >> 6;
    int wr = wid >> 1, wc = wid & 1;
    int lr = lane & 15;
    int lg = lane >> 4;
    int xoff = (lane & 7) << 3;

    f32x4 acc[2][4] = {};

    for (int k0 = 0; k0 < K; k0 += 64) {
#pragma unroll
        for (int c = 0; c < 2; ++c) {
            int ch = c * 256 + tid;
            int row = ch >> 3;
            int g8 = (ch & 7) ^ (row & 7);
            gload_lds16(Ab + (size_t)row * K + k0 + g8 * 8, sA + ch * 8);
        }
#pragma unroll
        for (int c = 0; c < 4; ++c) {
            int ch = c * 256 + tid;
            int row = ch >> 3;
            int g8 = (ch & 7) ^ (row & 7);
            gload_lds16(Bb + (size_t)row * K + k0 + g8 * 8, sB + ch * 8);
        }
        __syncthreads();
#pragma unroll
        for (int kk = 0; kk < 2; ++kk) {
            int kb = (kk * 32 + lg * 8) ^ xoff;
            bf16x8 af[2], bfr[4];
#pragma unroll
            for (int m = 0; m < 2; ++m)
                af[m] = *(const bf16x8*)&sA[(wr * 32 + m * 16 + lr) * 64 + kb];
#pragma unroll
            for (int n = 0; n < 4; ++n)
                bfr[n] = *(const bf16x8*)&sB[(wc * 64 + n * 16 + lr) * 64 + kb];
#pragma unroll
            for (int m = 0; m < 2; ++m)
#pragma unroll
                for (int n = 0; n < 4; ++n)
                    acc[m][n] = __builtin_amdgcn_mfma_f32_16x16x32_bf16(af[m], bfr[n], acc[m][n], 0, 0, 0);
        }
        __syncthreads();
    }

#pragma unroll
    for (int m = 0; m < 2; ++m) {
        int r0 = wr * 32 + m * 16 + lg * 4;
#pragma unroll
        for (int n = 0; n < 4; ++n) {
            int c0 = wc * 64 + n * 16 + lr;
#pragma unroll
            for (int j = 0; j < 4; ++j)
                st[(r0 + j) * 132 + c0] = acc[m][n][j];
        }
    }
    __syncthreads();
    int r  = tid >> 2;
    int c0 = (tid & 3) * 32;
    size_t grow = (size_t)(by * 64 + r) * N + bx * 128 + c0;
#pragma unroll
    for (int g = 0; g < 4; ++g) {
        f32x4 a = *(const f32x4*)&st[r * 132 + c0 + g * 8];
        f32x4 b = *(const f32x4*)&st[r * 132 + c0 + g * 8 + 4];
        u16x8 o;
#pragma unroll
        for (int j = 0; j < 4; ++j) { o[j] = f2bf(a[j]); o[4 + j] = f2bf(b[j]); }
        *(u16x8*)&C[grow + g * 8] = o;
    }
}

__global__ __launch_bounds__(256) void kn_proj(const unsigned short* __restrict__ Hbf,
                                               const unsigned short* __restrict__ Wkbf,
                                               unsigned short* __restrict__ Kbf,
                                               const float* __restrict__ G,
                                               const unsigned short* __restrict__ Wqbf,
                                               unsigned short* __restrict__ Qbf,
                                               int Dp, int Dh, int Dg) {
    __shared__ __align__(16) char smem_raw[64 * 132 * 4];
    int wg = blockIdx.x;
    if (wg < 512) kproj_body(smem_raw, Hbf, Wkbf, Kbf, Dp, Dh, wg);
    else          qproj_body(smem_raw, G, Wqbf, Qbf, Dp, Dg, wg - 512);
}

// ------- S-GEMM: 256x128, BK=64, 8 waves, single-buffer; exp + rowsum epilogue -------
__global__ __launch_bounds__(512) void kn_sgemm(const unsigned short* __restrict__ A,
                                                const unsigned short* __restrict__ B,
                                                unsigned short* __restrict__ C,
                                                float* __restrict__ rowsum,
                                                int N, int K, int Trows,
                                                long batchA, long batchB, long batchC,
                                                float scale, int gxs) {
    __shared__ __align__(16) char smem_raw[49152];
    unsigned short* base = (unsigned short*)smem_raw;
    float* st = (float*)smem_raw;

    int tid = threadIdx.x;
    int wg = blockIdx.x;
    int bz = wg & 7;
    int t = wg >> 3;
    int by = t >> gxs;
    int bx = t & ((1 << gxs) - 1);

    const unsigned short* Ab = A + (size_t)bz * batchA + (size_t)by * 256 * K;
    const unsigned short* Bb = B + (size_t)bz * batchB + (size_t)bx * 128 * K;
    unsigned short* Cb = C + (size_t)bz * batchC;
    float* rs = rowsum + (size_t)bz * Trows;

    int lane = tid & 63;
    int wid = tid >> 6;
    int wr = wid >> 1, wc = wid & 1;
    int lr = lane & 15;
    int lg = lane >> 4;
    int xoff = (lane & 7) << 3;

    f32x4 acc[4][4] = {};

    for (int k0 = 0; k0 < K; k0 += 64) {
#pragma unroll
        for (int c = 0; c < 6; ++c) {
            int ch = c * 512 + tid;
            if (ch < 2048) {
                int row = ch >> 3;
                int g8 = (ch & 7) ^ (row & 7);
                gload_lds16(Ab + (size_t)row * K + k0 + g8 * 8, base + ch * 8);
            } else {
                int bc = ch - 2048;
                int row = bc >> 3;
                int g8 = (bc & 7) ^ (row & 7);
                gload_lds16(Bb + (size_t)row * K + k0 + g8 * 8, base + 16384 + bc * 8);
            }
        }
        __syncthreads();
#pragma unroll
        for (int kk = 0; kk < 2; ++kk) {
            int kb = (kk * 32 + lg * 8) ^ xoff;
            bf16x8 af[4], bfr[4];
#pragma unroll
            for (int m = 0; m < 4; ++m)
                af[m] = *(const bf16x8*)&base[(wr * 64 + m * 16 + lr) * 64 + kb];
#pragma unroll
            for (int n = 0; n < 4; ++n)
                bfr[n] = *(const bf16x8*)&base[16384 + (wc * 64 + n * 16 + lr) * 64 + kb];
#pragma unroll
            for (int m = 0; m < 4; ++m)
#pragma unroll
                for (int n = 0; n < 4; ++n)
                    acc[m][n] = __builtin_amdgcn_mfma_f32_16x16x32_bf16(af[m], bfr[n], acc[m][n], 0, 0, 0);
        }
        __syncthreads();
    }

#pragma unroll
    for (int q = 0; q < 4; ++q) {
        if (wr == q) {
#pragma unroll
            for (int m = 0; m < 4; ++m) {
                int rl = m * 16 + lg * 4;
#pragma unroll
                for (int n = 0; n < 4; ++n) {
                    int col = wc * 64 + n * 16 + lr;
#pragma unroll
                    for (int j = 0; j < 4; ++j)
                        st[(rl + j) * 132 + col] = acc[m][n][j] * scale;
                }
            }
        }
        __syncthreads();
        int r = tid >> 3;
        int c0 = (tid & 7) * 16;
        int grow_r = by * 256 + q * 64 + r;
        size_t grow = (size_t)grow_r * N + bx * 128 + c0;
        float psum = 0.f;
#pragma unroll
        for (int g = 0; g < 2; ++g) {
            f32x4 a = *(const f32x4*)&st[r * 132 + c0 + g * 8];
            f32x4 b = *(const f32x4*)&st[r * 132 + c0 + g * 8 + 4];
            u16x8 o;
#pragma unroll
            for (int j = 0; j < 4; ++j) {
                o[j]     = f2bf(__expf(a[j]));
                o[4 + j] = f2bf(__expf(b[j]));
                psum += bf2f(o[j]) + bf2f(o[4 + j]);
            }
            *(u16x8*)&Cb[grow + g * 8] = o;
        }
        psum += __shfl_xor(psum, 1);
        psum += __shfl_xor(psum, 2);
        psum += __shfl_xor(psum, 4);
        if ((tid & 7) == 0)
            atomicAdd(&rs[grow_r], psum);
        __syncthreads();
    }
}

// ------- PV: 256x128, BK=64, 8 waves, 2-buf prefetch, 1 syncthreads/tile;
//         epilogue divides by rowsum. -------
__global__ __launch_bounds__(512) void kn_pv(const unsigned short* __restrict__ A,
                                             const unsigned short* __restrict__ B,
                                             float* __restrict__ C,
                                             const float* __restrict__ rowsum,
                                             int N, int K, int Trows,
                                             long batchA, long batchB, long batchC,
                                             int gxs) {
    __shared__ __align__(16) char smem_raw[2 * 49152];       // 96KB: 2 bufs (A32+B16)
    unsigned short* base = (unsigned short*)smem_raw;
    float* st = (float*)smem_raw;

    int tid = threadIdx.x;
    int wg = blockIdx.x;
    int bz = wg & 7;
    int t = wg >> 3;
    int by = t >> gxs;
    int bx = t & ((1 << gxs) - 1);

    const unsigned short* Ab = A + (size_t)bz * batchA + (size_t)by * 256 * K;
    const unsigned short* Bb = B + (size_t)bz * batchB + (size_t)bx * 128 * K;
    float* Cb = C + (size_t)bz * batchC;
    const float* rs = rowsum + (size_t)bz * Trows;

    int lane = tid & 63;
    int wid = tid >> 6;
    int wr = wid >> 1, wc = wid & 1;
    int lr = lane & 15;
    int lg = lane >> 4;
    int xoff = (lane & 7) << 3;

    f32x4 acc[4][4] = {};

    auto STAGE = [&](int buf, int k0) {
        unsigned short* dA = base + buf * 24576;
        unsigned short* dB = dA + 16384;
#pragma unroll
        for (int c = 0; c < 6; ++c) {
            int ch = c * 512 + tid;
            if (ch < 2048) {
                int row = ch >> 3;
                int g8 = (ch & 7) ^ (row & 7);
                gload_lds16(Ab + (size_t)row * K + k0 + g8 * 8, dA + ch * 8);
            } else {
                int bc = ch - 2048;
                int row = bc >> 3;
                int g8 = (bc & 7) ^ (row & 7);
                gload_lds16(Bb + (size_t)row * K + k0 + g8 * 8, dB + bc * 8);
            }
        }
    };
    auto COMPUTE = [&](int buf) {
        unsigned short* pA = base + buf * 24576;
        unsigned short* pB = pA + 16384;
#pragma unroll
        for (int kk = 0; kk < 2; ++kk) {
            int kb = (kk * 32 + lg * 8) ^ xoff;
            bf16x8 af[4], bfr[4];
#pragma unroll
            for (int m = 0; m < 4; ++m)
                af[m] = *(const bf16x8*)&pA[(wr * 64 + m * 16 + lr) * 64 + kb];
#pragma unroll
            for (int n = 0; n < 4; ++n)
                bfr[n] = *(const bf16x8*)&pB[(wc * 64 + n * 16 + lr) * 64 + kb];
#pragma unroll
            for (int m = 0; m < 4; ++m)
#pragma unroll
                for (int n = 0; n < 4; ++n)
                    acc[m][n] = __builtin_amdgcn_mfma_f32_16x16x32_bf16(af[m], bfr[n], acc[m][n], 0, 0, 0);
        }
    };

    int nt = K / 64;                           // 32
    STAGE(0, 0);
    __syncthreads();
    int cur = 0;
    for (int tt = 0; tt < nt; ++tt) {
        if (tt + 1 < nt) STAGE(cur ^ 1, (tt + 1) * 64);  // prefetch overlaps compute
        COMPUTE(cur);
        __syncthreads();                                 // drains vmcnt, fences bufs
        cur ^= 1;
    }

    // epilogue: 4 quarters via st[64][132], divide by rowsum
#pragma unroll
    for (int q = 0; q < 4; ++q) {
        if (wr == q) {
#pragma unroll
            for (int m = 0; m < 4; ++m) {
                int rl = m * 16 + lg * 4;
#pragma unroll
                for (int n = 0; n < 4; ++n) {
                    int col = wc * 64 + n * 16 + lr;
#pragma unroll
                    for (int j = 0; j < 4; ++j)
                        st[(rl + j) * 132 + col] = acc[m][n][j];
                }
            }
        }
        __syncthreads();
        int r = tid >> 3;
        int c0 = (tid & 7) * 16;
        float inv = 1.0f / rs[by * 256 + q * 64 + r];
        size_t grow = (size_t)(by * 256 + q * 64 + r) * N + bx * 128 + c0;
#pragma unroll
        for (int g = 0; g < 4; ++g) {
            f32x4 v = *(const f32x4*)&st[r * 132 + c0 + g * 4];
#pragma unroll
            for (int j = 0; j < 4; ++j) v[j] *= inv;
            *(f32x4*)&Cb[grow + g * 4] = v;
        }
        __syncthreads();
    }
}

extern "C" void kernel_launch(void* const* d_in, const int* in_sizes, int n_in,
                              void* d_out, int out_size, void* d_ws, size_t ws_size,
                              hipStream_t stream) {
    constexpr int B = 8, L = 2048, T = 1024, Dh = 1024, Dg = 768, Dp = 256;
    const float* H  = (const float*)d_in[0];
    const float* G  = (const float*)d_in[1];
    const float* Wq = (const float*)d_in[2];
    const float* Wk = (const float*)d_in[3];
    float* Z = (float*)d_out;

    unsigned short* Qbf  = (unsigned short*)d_ws;            // B*T*Dp  = 2M
    unsigned short* Kbf  = Qbf + (size_t)B * T * Dp;         // B*L*Dp  = 4M
    unsigned short* HT   = Kbf + (size_t)B * L * Dp;         // B*Dh*L  = 16M
    unsigned short* S    = HT  + (size_t)B * Dh * L;         // B*T*L   = 16M
    unsigned short* Hbf  = S   + (size_t)B * T * L;          // B*L*Dh  = 16M
    unsigned short* Wqbf = Hbf + (size_t)B * L * Dh;         // Dp*Dg
    unsigned short* Wkbf = Wqbf + (size_t)Dp * Dg;           // Dp*Dh
    float* rowsum = (float*)(Wkbf + (size_t)Dp * Dh);        // B*T f32

    int nq8 = Dp * Dg / 8, nk8 = Dp * Dh / 8;

    // 1. HT + Hbf from H, with W-cast + rowsum-zero fused onto low blocks
    kn_transp<<<dim3(Dh / 64, L / 64, B), dim3(256), 0, stream>>>
        (H, HT, Hbf, Wq, Wk, Wqbf, Wkbf, rowsum, L, Dh, nq8, nk8, B * T / 4);

    // 2. merged projections: 512 kproj blocks + 512 qproj blocks
    kn_proj<<<1024, 256, 0, stream>>>(Hbf, Wkbf, Kbf, G, Wqbf, Qbf, Dp, Dh, Dg);

    // 3. Sexp = exp(Q@K^T/16) + rowsum
    kn_sgemm<<<(T / 256) * (L / 128) * B, 512, 0, stream>>>
        (Qbf, Kbf, S, rowsum, L, Dp, T, (long)T * Dp, (long)L * Dp, (long)T * L, 0.0625f, 4);

    // 4. Z = (Sexp @ HT^T)/rowsum
    kn_pv<<<(T / 256) * (Dh / 128) * B, 512, 0, stream>>>
        (S, HT, Z, rowsum, Dh, L, T, (long)T * L, (long)Dh * L, (long)T * Dh, 3);
}